// Round 16
// baseline (325.656 us; speedup 1.0000x reference)
//
#include <hip/hip_runtime.h>
#include <hip/hip_bf16.h>
#include <cstdint>
#include <cstddef>

typedef unsigned short ushort_t;
typedef __bf16 bf16x8v __attribute__((ext_vector_type(8)));
typedef float f32x4 __attribute__((ext_vector_type(4)));

// Problem constants (from reference setup_inputs)
#define Bsz 4
#define Sseq 2048
#define Dd 1024
#define DFFd 4096
#define Ee 8
#define DFEd 1024
#define IDCUT 1024          // id = S//2
#define NTOK (Bsz*Sseq)     // 8192
#define NMOE (Bsz*(Sseq-IDCUT)) // 4096 MoE tokens
#define MAXSLOT 4096        // max slots per expert (observed ~1024, 4x headroom)

__device__ __forceinline__ ushort_t f2bf(float f) {
  unsigned u = __float_as_uint(f);
  u += 0x7fffu + ((u >> 16) & 1u);       // round-to-nearest-even
  return (ushort_t)(u >> 16);
}

__device__ __forceinline__ unsigned pk2bf(float a, float b) {
  return (unsigned)f2bf(a) | ((unsigned)f2bf(b) << 16);
}

// gelu(tanh approx) == x * sigmoid(1.5957691*(x + 0.044715 x^3)); exp+rcp (~8 VALU)
__device__ __forceinline__ float gelu_f(float x) {
  float u = x * (1.0f + 0.044715f * x * x);
  float s = 1.0f / (1.0f + __expf(-1.5957691216057308f * u));
  return x * s;
}

__device__ __forceinline__ void gload_lds16(const void* g, void* l) {
  __builtin_amdgcn_global_load_lds(
      (const __attribute__((address_space(1))) void*)g,
      (__attribute__((address_space(3))) void*)l,
      16, 0, 0);
}

// ---------------- device fns: cast / router / transpose ----------------
__device__ __forceinline__ void cast_dev(const float* __restrict__ x,
                                         ushort_t* __restrict__ xb, int wg) {
  const int row  = wg * 4 + (threadIdx.x >> 6);
  const int lane = threadIdx.x & 63;
  const float* xr = x + (size_t)row * Dd;
  ushort_t* xbr = xb + (size_t)row * Dd;
  float4 v[4];
  #pragma unroll
  for (int j = 0; j < 4; ++j) v[j] = ((const float4*)xr)[lane + j * 64];
  #pragma unroll
  for (int j = 0; j < 4; ++j) {
    ushort4 o;
    o.x = f2bf(v[j].x); o.y = f2bf(v[j].y); o.z = f2bf(v[j].z); o.w = f2bf(v[j].w);
    ((ushort4*)xbr)[lane + j * 64] = o;
  }
}

// 64 tokens/block; LDS-aggregated slot alloc: ONE atomicAdd per (block,expert).
__device__ __forceinline__ void router_dev(
    const float* __restrict__ x, const float* __restrict__ Wg,
    int* __restrict__ cnt, int* __restrict__ slots, float* __restrict__ gsv,
    int blk, int* __restrict__ eTok, int* __restrict__ lbase)
{
  const int wid = threadIdx.x >> 6, lane = threadIdx.x & 63;
  const int tblk = blk * 64;

  #pragma unroll 1
  for (int it = 0; it < 16; ++it) {
    const int ti = it * 4 + wid;          // token within block [0,64)
    const int t  = tblk + ti;             // global MoE token [0,4096)
    const int b  = t >> 10, s = (t & 1023) + IDCUT;
    const float* xr = x + ((size_t)b * Sseq + s) * Dd;
    float4 accA = {0.f,0.f,0.f,0.f}, accB = {0.f,0.f,0.f,0.f};
    #pragma unroll
    for (int j = 0; j < 4; ++j) {
      const float4 v = ((const float4*)xr)[lane + j * 64];
      const int kbase = (lane + j * 64) * 4;
      #pragma unroll
      for (int r = 0; r < 4; ++r) {
        const float xv = (r == 0) ? v.x : (r == 1) ? v.y : (r == 2) ? v.z : v.w;
        const float4 wa = *(const float4*)(Wg + (size_t)(kbase + r) * 8);
        const float4 wb = *(const float4*)(Wg + (size_t)(kbase + r) * 8 + 4);
        accA.x += xv * wa.x; accA.y += xv * wa.y; accA.z += xv * wa.z; accA.w += xv * wa.w;
        accB.x += xv * wb.x; accB.y += xv * wb.y; accB.z += xv * wb.z; accB.w += xv * wb.w;
      }
    }
    float acc[8] = {accA.x, accA.y, accA.z, accA.w, accB.x, accB.y, accB.z, accB.w};
    #pragma unroll
    for (int off = 32; off > 0; off >>= 1) {
      #pragma unroll
      for (int e8 = 0; e8 < 8; ++e8) acc[e8] += __shfl_xor(acc[e8], off);
    }
    if (lane == 0) {
      int e0 = 0; float v0 = acc[0];
      #pragma unroll
      for (int e8 = 1; e8 < 8; ++e8) if (acc[e8] > v0) { v0 = acc[e8]; e0 = e8; }
      int e1 = -1; float v1 = -3.4e38f;
      #pragma unroll
      for (int e8 = 0; e8 < 8; ++e8) if (e8 != e0 && acc[e8] > v1) { v1 = acc[e8]; e1 = e8; }
      float g0 = 1.0f / (1.0f + expf(v1 - v0));   // = p0/(p0+p1) via softmax monotonicity
      eTok[ti * 2] = e0; eTok[ti * 2 + 1] = e1;
      gsv[t * 2] = g0;  gsv[t * 2 + 1] = 1.0f - g0;
    }
  }
  __syncthreads();
  if (wid == 0) {
    int cnts[8] = {0,0,0,0,0,0,0,0};
    int el[2];
    #pragma unroll
    for (int p = 0; p < 2; ++p) {
      el[p] = eTok[p * 64 + lane];
      #pragma unroll
      for (int e = 0; e < 8; ++e)
        cnts[e] += __popcll(__ballot(el[p] == e));
    }
    if (lane < 8) lbase[lane] = atomicAdd(&cnt[lane], cnts[lane]);
    int run[8];
    #pragma unroll
    for (int e = 0; e < 8; ++e) run[e] = lbase[e];   // LDS RAW within wave: HW-ordered
    #pragma unroll
    for (int p = 0; p < 2; ++p) {
      const int ent = p * 64 + lane;
      const int val = (tblk + (ent >> 1)) * 2 + (ent & 1);
      #pragma unroll
      for (int e = 0; e < 8; ++e) {
        unsigned long long m = __ballot(el[p] == e);
        if (el[p] == e)
          slots[e * MAXSLOT + run[e] + __popcll(m & ((1ull << lane) - 1ull))] = val;
        run[e] += __popcll(m);
      }
    }
  }
}

// 64x128 transpose tile: in [R][C] fp32 -> out [C][R] bf16, 16B stores.
__device__ __forceinline__ void t64x128(const float* __restrict__ in,
                                        ushort_t* __restrict__ out,
                                        int R, int C, int by, int bx,
                                        float* __restrict__ lds) {
  const int t = threadIdx.x;
  const int c4 = t & 31;
  const int r0 = t >> 5;
  const float* src = in + (size_t)(by * 64) * C + bx * 128;
  #pragma unroll
  for (int p = 0; p < 8; ++p) {
    const int r = r0 + p * 8;
    const float4 vv = *(const float4*)(src + (size_t)r * C + c4 * 4);
    *(float4*)(lds + r * 129 + c4 * 4) = vv;
  }
  __syncthreads();
  ushort_t* dst = out + (size_t)(bx * 128) * R + by * 64;
  const int rr0 = (t & 7) * 8;
  #pragma unroll
  for (int p = 0; p < 4; ++p) {
    const int cc = (t >> 3) + p * 32;
    const float* col = lds + (size_t)rr0 * 129 + cc;
    float f0 = col[0*129], f1 = col[1*129], f2 = col[2*129], f3 = col[3*129];
    float f4 = col[4*129], f5 = col[5*129], f6 = col[6*129], f7 = col[7*129];
    uint4 q;
    q.x = pk2bf(f0, f1); q.y = pk2bf(f2, f3);
    q.z = pk2bf(f4, f5); q.w = pk2bf(f6, f7);
    *(uint4*)(dst + (size_t)cc * R + rr0) = q;
  }
}

// ---------------- prep1: router FIRST, then cast, then W1t/We1t transposes ----------------
// Router blocks are the longest; dispatching them at wg<64 puts them in the
// first occupancy wave instead of serializing at the tail (round-15: ~+5us).
__global__ __launch_bounds__(256) void prep1_k(
    const float* __restrict__ x, ushort_t* __restrict__ xb,
    const float* __restrict__ Wg,
    int* __restrict__ cnt, int* __restrict__ slots, float* __restrict__ gsv,
    const float* __restrict__ W1, ushort_t* __restrict__ W1t,
    const float* __restrict__ We1, ushort_t* __restrict__ We1t)
{
  __shared__ char smemraw[64 * 129 * 4];
  const int wg = blockIdx.x;
  if (wg < 64) {
    router_dev(x, Wg, cnt, slots, gsv, wg,
               (int*)smemraw, (int*)(smemraw + 512));
  } else if (wg < 2112) {
    cast_dev(x, xb, wg - 64);
  } else if (wg < 2624) {               // W1: R=1024 C=4096, 16x32 tiles
    const int i = wg - 2112;
    t64x128(W1, W1t, Dd, DFFd, i >> 5, i & 31, (float*)smemraw);
  } else {                              // We1: 8 x (16x8 tiles)
    const int i = wg - 2624, z = i >> 7, rem = i & 127;
    t64x128(We1 + (size_t)z * Dd * DFEd, We1t + (size_t)z * Dd * DFEd,
            Dd, DFEd, rem >> 3, rem & 7, (float*)smemraw);
  }
}

// ================= 128x128 BK=64 m97-structure tile =================
// 4 waves (2x2 of 64x64), single-buffer 32KB LDS, 8-way XOR swizzle
// (source col pre-permuted, read XOR'd back).
// MODE 0: FFN1 gelu->bf16 | 1: FFN2 direct fp32 store | 2: MoE1 gather gelu->bf16
// MODE 3: MoE2 gather, eo[sv] = gate*(acc+bias)  (plain keyed store, no atomics)
template<int MODE>
__device__ __forceinline__ void gemm_tile(
    int nt, int mt, int e,
    const ushort_t* __restrict__ A, const ushort_t* __restrict__ Bt,
    const float* __restrict__ biase, void* __restrict__ C,
    int M, int lda, int N, int ldc,
    const int* __restrict__ cnt, const int* __restrict__ slots,
    const float* __restrict__ gates,
    ushort_t* Al, ushort_t* Bl)
{
  int rows = M;
  const int* slist = nullptr;
  if (MODE >= 2) {
    rows = cnt[e];
    if (mt * 128 >= rows) return;
    slist = slots + e * MAXSLOT;
  }
  const ushort_t* Bte = (MODE >= 2) ? (Bt + (size_t)e * (size_t)lda * (size_t)N) : Bt;

  const int tid  = threadIdx.x;
  const int lane = tid & 63;
  const int wid  = tid >> 6;
  const int wr   = wid >> 1, wc = wid & 1;
  const int lr   = lane & 15;
  const int lg   = lane >> 4;
  const int swz7 = lane & 7;   // == row&7 on the read side (rows stride 16)

  // --- staging source pointers: 4 slots/thread per matrix, pre-swizzled col ---
  const ushort_t* gA[4];
  const ushort_t* gB[4];
  #pragma unroll
  for (int j = 0; j < 4; ++j) {
    int tt = j * 256 + tid;
    int rl = tt >> 3, slot = tt & 7;
    int col8 = slot ^ (rl & 7);
    int grow = mt * 128 + rl;
    size_t rowoff;
    if (MODE < 2) {
      rowoff = (size_t)grow;
    } else {
      int idx = grow > rows - 1 ? rows - 1 : grow;
      int sv = slist[idx];
      if (MODE == 2) { int t = sv >> 1; rowoff = (size_t)((t >> 10) * Sseq + IDCUT + (t & 1023)); }
      else           { rowoff = (size_t)sv; }
    }
    gA[j] = A + rowoff * (size_t)lda + col8 * 8;
    gB[j] = Bte + (size_t)(nt * 128 + rl) * (size_t)lda + col8 * 8;
  }

  f32x4 acc[4][4];
  const f32x4 vzero = {0.f, 0.f, 0.f, 0.f};
  #pragma unroll
  for (int m = 0; m < 4; ++m)
    #pragma unroll
    for (int n = 0; n < 4; ++n) acc[m][n] = vzero;

  const unsigned aRow = (unsigned)((wr * 64 + lr) * 128);
  const unsigned bRow = (unsigned)((wc * 64 + lr) * 128);
  const unsigned s0 = (unsigned)((lg ^ swz7) << 4);        // ks=0 slot
  const unsigned s1 = (unsigned)(((4 + lg) ^ swz7) << 4);  // ks=1 slot

  for (int k0 = 0; k0 < lda; k0 += 64) {
    __syncthreads();
    #pragma unroll
    for (int j = 0; j < 4; ++j)
      gload_lds16(gA[j] + k0, (void*)((char*)Al + (j * 256 + wid * 64) * 16));
    #pragma unroll
    for (int j = 0; j < 4; ++j)
      gload_lds16(gB[j] + k0, (void*)((char*)Bl + (j * 256 + wid * 64) * 16));
    __syncthreads();   // compiler inserts vmcnt(0)+lgkmcnt(0) drain (m97 pattern)

    {  // ks = 0
      bf16x8v af[4], bfr[4];
      #pragma unroll
      for (int mi = 0; mi < 4; ++mi)
        af[mi] = *(const bf16x8v*)((const char*)Al + aRow + mi * 2048 + s0);
      #pragma unroll
      for (int ni = 0; ni < 4; ++ni)
        bfr[ni] = *(const bf16x8v*)((const char*)Bl + bRow + ni * 2048 + s0);
      #pragma unroll
      for (int mi = 0; mi < 4; ++mi)
        #pragma unroll
        for (int ni = 0; ni < 4; ++ni)
          acc[mi][ni] = __builtin_amdgcn_mfma_f32_16x16x32_bf16(
              af[mi], bfr[ni], acc[mi][ni], 0, 0, 0);
    }
    {  // ks = 1
      bf16x8v af[4], bfr[4];
      #pragma unroll
      for (int mi = 0; mi < 4; ++mi)
        af[mi] = *(const bf16x8v*)((const char*)Al + aRow + mi * 2048 + s1);
      #pragma unroll
      for (int ni = 0; ni < 4; ++ni)
        bfr[ni] = *(const bf16x8v*)((const char*)Bl + bRow + ni * 2048 + s1);
      #pragma unroll
      for (int mi = 0; mi < 4; ++mi)
        #pragma unroll
        for (int ni = 0; ni < 4; ++ni)
          acc[mi][ni] = __builtin_amdgcn_mfma_f32_16x16x32_bf16(
              af[mi], bfr[ni], acc[mi][ni], 0, 0, 0);
    }
  }

  // --- epilogue: C/D layout col = lane&15, row = (lane>>4)*4 + jj ---
  #pragma unroll
  for (int mf = 0; mf < 4; ++mf) {
    #pragma unroll
    for (int jj = 0; jj < 4; ++jj) {
      const int lrow = wr * 64 + mf * 16 + lg * 4 + jj;
      const int grow = mt * 128 + lrow;
      size_t crow; float gt = 0.f;
      if (MODE >= 2) {
        if (grow >= rows) continue;
        int sv = slist[grow];
        crow = (size_t)sv;
        if (MODE == 3) gt = gates[sv];
      } else {
        crow = (size_t)grow;
      }
      #pragma unroll
      for (int nf = 0; nf < 4; ++nf) {
        const int gcol = nt * 128 + wc * 64 + nf * 16 + lr;
        float v = acc[mf][nf][jj] + biase[gcol];
        if (MODE == 0 || MODE == 2) {
          ((ushort_t*)C)[crow * (size_t)ldc + gcol] = f2bf(gelu_f(v));
        } else if (MODE == 1) {
          ((float*)C)[crow * (size_t)ldc + gcol] = v;
        } else {
          ((float*)C)[crow * (size_t)ldc + gcol] = gt * v;   // eo, plain store
        }
      }
    }
  }
}

// FFN1 (2048) + MoE1 (2048) + W2t/We2t transpose backfill tail (1536).
// XCD-banded maps (XCD = blockIdx % 8):
//  FFN1: XCD owns mt-band; 8mt x 8nt co-resident squares (A+B ~ L2).
//  MoE1: expert e pinned to XCD e -> We1t[e] in one L2 only.
//  Tail transposes run in the drain tail; W2t/We2t consumed by NEXT launches.
__global__ __launch_bounds__(256, 3) void fused1_k(
    const ushort_t* __restrict__ xb,
    const ushort_t* __restrict__ W1t, const float* __restrict__ b1, ushort_t* __restrict__ h1,
    const ushort_t* __restrict__ We1t, const float* __restrict__ be1, ushort_t* __restrict__ hs,
    const int* __restrict__ cnt, const int* __restrict__ slots,
    const float* __restrict__ W2, ushort_t* __restrict__ W2t,
    const float* __restrict__ We2, ushort_t* __restrict__ We2t)
{
  __shared__ char smemraw[64 * 129 * 4];   // 33024B: max(GEMM 32KB, transpose 33KB)
  ushort_t* Al = (ushort_t*)smemraw;
  ushort_t* Bl = (ushort_t*)(smemraw + 16384);
  int wg = blockIdx.x;
  if (wg < 2048) {
    int xcd = wg & 7, idx = wg >> 3;            // idx in [0,256)
    int ntB = idx >> 6, mtL = (idx >> 3) & 7, ntS = idx & 7;
    int mt = xcd * 8 + mtL, nt = ntB * 8 + ntS;
    gemm_tile<0>(nt, mt, 0, xb, W1t, b1, (void*)h1, NTOK, Dd, DFFd, DFFd,
                 nullptr, nullptr, nullptr, Al, Bl);
  } else if (wg < 4096) {
    int i = wg - 2048;                          // i mod 8 == wg mod 8
    int e = i & 7, j = i >> 3;                  // j in [0,256)
    int mt = j >> 3, nt = j & 7;
    gemm_tile<2>(nt, mt, e, xb, We1t, be1 + e * DFEd, (void*)hs, 0, Dd, DFEd, DFEd,
                 cnt, slots, nullptr, Al, Bl);
  } else if (wg < 4608) {                       // W2: R=4096 C=1024, 64x8 tiles
    const int i = wg - 4096;
    t64x128(W2, W2t, DFFd, Dd, i >> 3, i & 7, (float*)smemraw);
  } else {                                      // We2: 8 x (16x8 tiles)
    const int i = wg - 4608, z = i >> 7, rem = i & 127;
    t64x128(We2 + (size_t)z * DFEd * Dd, We2t + (size_t)z * DFEd * Dd,
            DFEd, Dd, rem >> 3, rem & 7, (float*)smemraw);
  }
}

// FFN2 (512 long blocks, dispatched FIRST) + MoE2 (2048 short blocks backfill).
// Disjoint outputs (out vs eo) -> safe in one launch. Round-16: (256,4) —
// 4 blocks/CU (LDS 128KB, reg cap 128: acc 64 + ~60 arch) for more
// cross-block drain overlap on the K=4096 loop.
__global__ __launch_bounds__(256, 4) void fused2_k(
    const ushort_t* __restrict__ h1,
    const ushort_t* __restrict__ W2t, const float* __restrict__ b2,
    float* __restrict__ out,
    const ushort_t* __restrict__ hs,
    const ushort_t* __restrict__ We2t, const float* __restrict__ be2,
    float* __restrict__ eo,
    const int* __restrict__ cnt, const int* __restrict__ slots,
    const float* __restrict__ gsv)
{
  __shared__ ushort_t Al[128 * 64];
  __shared__ ushort_t Bl[128 * 64];
  int wg = blockIdx.x;
  if (wg < 512) {
    // FFN2: XCD owns mt-band [xcd*8, xcd*8+8) x all 8 nt (co-resident)
    int xcd = wg & 7, idx = wg >> 3;            // idx in [0,64)
    int nt = idx >> 3, mtL = idx & 7;
    int mt = xcd * 8 + mtL;
    gemm_tile<1>(nt, mt, 0, h1, W2t, b2, (void*)out, NTOK, DFFd, Dd, Dd,
                 nullptr, nullptr, nullptr, Al, Bl);
  } else {
    // MoE2: expert e pinned to XCD e; eo[sv] = gate*(acc+be2)
    int i = wg - 512;                           // i mod 8 == wg mod 8
    int e = i & 7, j = i >> 3;                  // j in [0,256)
    int mt = j >> 3, nt = j & 7;
    gemm_tile<3>(nt, mt, e, hs, We2t, be2 + e * Dd, (void*)eo, 0, DFEd, Dd, Dd,
                 cnt, slots, gsv, Al, Bl);
  }
}

// combine: out[moe rows] += LAM*(eo[2t] + eo[2t+1]); 4 float4/thread for ILP
__global__ __launch_bounds__(256) void combine_k(
    float* __restrict__ out, const float* __restrict__ eo)
{
  const int base = blockIdx.x * 256 + threadIdx.x;   // 1024 blocks
  #pragma unroll
  for (int p = 0; p < 4; ++p) {
    const int i = p * (1024 * 256) + base;           // stride passes: coalesced
    const int t = i >> 8;                            // 256 float4 per row
    const int c4 = i & 255;
    const size_t r = (size_t)((t >> 10) * Sseq + IDCUT + (t & 1023));
    const float4 a = ((const float4*)(eo + (size_t)(2 * t) * Dd))[c4];
    const float4 b = ((const float4*)(eo + (size_t)(2 * t + 1) * Dd))[c4];
    float4* op = (float4*)(out + r * Dd);
    float4 o = op[c4];
    o.x += 0.5f * (a.x + b.x);
    o.y += 0.5f * (a.y + b.y);
    o.z += 0.5f * (a.z + b.z);
    o.w += 0.5f * (a.w + b.w);
    op[c4] = o;
  }
}

// ---------------- workspace layout (bytes) ----------------
#define WS_XB    ((size_t)0)           // 16777216   xb bf16 [8192][1024]
#define WS_W1T   ((size_t)16777216)    //  8388608   W1^T bf16 [4096][1024]
#define WS_W2T   ((size_t)25165824)    //  8388608   W2^T bf16 [1024][4096]
#define WS_WE1T  ((size_t)33554432)    // 16777216   We1^T bf16 [8][1024][1024]
#define WS_WE2T  ((size_t)50331648)    // 16777216   We2^T bf16 [8][1024][1024]
#define WS_H1    ((size_t)67108864)    // 67108864   h1 bf16 [8192][4096]
#define WS_HS    ((size_t)134217728)   // 16777216   h_slot bf16 [8192][1024]
#define WS_EO    ((size_t)150994944)   // 33554432   eo fp32 [8192][1024]
#define WS_CNT   ((size_t)184549376)   // 256        cnt int[8]
#define WS_SLOT  ((size_t)184549632)   // 131072     slots int[8][4096]
#define WS_GSV   ((size_t)184680704)   // 32768      gate per slot fp32[8192]

extern "C" void kernel_launch(void* const* d_in, const int* in_sizes, int n_in,
                              void* d_out, int out_size, void* d_ws, size_t ws_size,
                              hipStream_t stream) {
  const float* x   = (const float*)d_in[0];
  const float* W1  = (const float*)d_in[1];
  const float* b1  = (const float*)d_in[2];
  const float* W2  = (const float*)d_in[3];
  const float* b2  = (const float*)d_in[4];
  const float* Wg  = (const float*)d_in[5];
  const float* We1 = (const float*)d_in[6];
  const float* be1 = (const float*)d_in[7];
  const float* We2 = (const float*)d_in[8];
  const float* be2 = (const float*)d_in[9];
  float* out = (float*)d_out;

  char* ws = (char*)d_ws;
  ushort_t* xb   = (ushort_t*)(ws + WS_XB);
  ushort_t* W1t  = (ushort_t*)(ws + WS_W1T);
  ushort_t* W2t  = (ushort_t*)(ws + WS_W2T);
  ushort_t* We1t = (ushort_t*)(ws + WS_WE1T);
  ushort_t* We2t = (ushort_t*)(ws + WS_WE2T);
  ushort_t* h1   = (ushort_t*)(ws + WS_H1);
  ushort_t* hs   = (ushort_t*)(ws + WS_HS);
  float*    eo   = (float*)(ws + WS_EO);
  int*      cnt  = (int*)(ws + WS_CNT);
  int*      slots= (int*)(ws + WS_SLOT);
  float*    gsv  = (float*)(ws + WS_GSV);

  hipMemsetAsync(cnt, 0, 8 * sizeof(int), stream);

  // prep1: router (64, first) + cast (2048) + W1t/We1t transposes (1536)
  prep1_k<<<dim3(3648), 256, 0, stream>>>(x, xb, Wg, cnt, slots, gsv,
                                          W1, W1t, We1, We1t);
  // FFN1 + MoE1 + W2t/We2t transpose backfill tail
  fused1_k<<<dim3(5632), 256, 0, stream>>>(xb, W1t, b1, h1, We1t, be1, hs,
                                           cnt, slots, W2, W2t, We2, We2t);
  // FFN2 (512, first) + MoE2 (2048, backfill) — disjoint outputs out / eo
  fused2_k<<<dim3(2560), 256, 0, stream>>>(h1, W2t, b2, out,
                                           hs, We2t, be2, eo, cnt, slots, gsv);
  // combine: out[moe rows] += LAM*(eo[2t]+eo[2t+1])
  combine_k<<<dim3(1024), 256, 0, stream>>>(out, eo);
}

// Round 17
// 271.147 us; speedup vs baseline: 1.2010x; 1.2010x over previous
//
#include <hip/hip_runtime.h>
#include <hip/hip_bf16.h>
#include <cstdint>
#include <cstddef>

typedef unsigned short ushort_t;
typedef __bf16 bf16x8v __attribute__((ext_vector_type(8)));
typedef float f32x4 __attribute__((ext_vector_type(4)));

// Problem constants (from reference setup_inputs)
#define Bsz 4
#define Sseq 2048
#define Dd 1024
#define DFFd 4096
#define Ee 8
#define DFEd 1024
#define IDCUT 1024          // id = S//2
#define NTOK (Bsz*Sseq)     // 8192
#define NMOE (Bsz*(Sseq-IDCUT)) // 4096 MoE tokens
#define MAXSLOT 4096        // max slots per expert (observed ~1024, 4x headroom)

__device__ __forceinline__ ushort_t f2bf(float f) {
  unsigned u = __float_as_uint(f);
  u += 0x7fffu + ((u >> 16) & 1u);       // round-to-nearest-even
  return (ushort_t)(u >> 16);
}

__device__ __forceinline__ unsigned pk2bf(float a, float b) {
  return (unsigned)f2bf(a) | ((unsigned)f2bf(b) << 16);
}

// gelu(tanh approx) == x * sigmoid(1.5957691*(x + 0.044715 x^3)); exp+rcp (~8 VALU)
__device__ __forceinline__ float gelu_f(float x) {
  float u = x * (1.0f + 0.044715f * x * x);
  float s = 1.0f / (1.0f + __expf(-1.5957691216057308f * u));
  return x * s;
}

__device__ __forceinline__ void gload_lds16(const void* g, void* l) {
  __builtin_amdgcn_global_load_lds(
      (const __attribute__((address_space(1))) void*)g,
      (__attribute__((address_space(3))) void*)l,
      16, 0, 0);
}

// ---------------- device fns: cast / router / transpose ----------------
__device__ __forceinline__ void cast_dev(const float* __restrict__ x,
                                         ushort_t* __restrict__ xb, int wg) {
  const int row  = wg * 4 + (threadIdx.x >> 6);
  const int lane = threadIdx.x & 63;
  const float* xr = x + (size_t)row * Dd;
  ushort_t* xbr = xb + (size_t)row * Dd;
  float4 v[4];
  #pragma unroll
  for (int j = 0; j < 4; ++j) v[j] = ((const float4*)xr)[lane + j * 64];
  #pragma unroll
  for (int j = 0; j < 4; ++j) {
    ushort4 o;
    o.x = f2bf(v[j].x); o.y = f2bf(v[j].y); o.z = f2bf(v[j].z); o.w = f2bf(v[j].w);
    ((ushort4*)xbr)[lane + j * 64] = o;
  }
}

// 64 tokens/block; LDS-aggregated slot alloc: ONE atomicAdd per (block,expert).
__device__ __forceinline__ void router_dev(
    const float* __restrict__ x, const float* __restrict__ Wg,
    int* __restrict__ cnt, int* __restrict__ slots, float* __restrict__ gsv,
    int blk, int* __restrict__ eTok, int* __restrict__ lbase)
{
  const int wid = threadIdx.x >> 6, lane = threadIdx.x & 63;
  const int tblk = blk * 64;

  #pragma unroll 1
  for (int it = 0; it < 16; ++it) {
    const int ti = it * 4 + wid;          // token within block [0,64)
    const int t  = tblk + ti;             // global MoE token [0,4096)
    const int b  = t >> 10, s = (t & 1023) + IDCUT;
    const float* xr = x + ((size_t)b * Sseq + s) * Dd;
    float4 accA = {0.f,0.f,0.f,0.f}, accB = {0.f,0.f,0.f,0.f};
    #pragma unroll
    for (int j = 0; j < 4; ++j) {
      const float4 v = ((const float4*)xr)[lane + j * 64];
      const int kbase = (lane + j * 64) * 4;
      #pragma unroll
      for (int r = 0; r < 4; ++r) {
        const float xv = (r == 0) ? v.x : (r == 1) ? v.y : (r == 2) ? v.z : v.w;
        const float4 wa = *(const float4*)(Wg + (size_t)(kbase + r) * 8);
        const float4 wb = *(const float4*)(Wg + (size_t)(kbase + r) * 8 + 4);
        accA.x += xv * wa.x; accA.y += xv * wa.y; accA.z += xv * wa.z; accA.w += xv * wa.w;
        accB.x += xv * wb.x; accB.y += xv * wb.y; accB.z += xv * wb.z; accB.w += xv * wb.w;
      }
    }
    float acc[8] = {accA.x, accA.y, accA.z, accA.w, accB.x, accB.y, accB.z, accB.w};
    #pragma unroll
    for (int off = 32; off > 0; off >>= 1) {
      #pragma unroll
      for (int e8 = 0; e8 < 8; ++e8) acc[e8] += __shfl_xor(acc[e8], off);
    }
    if (lane == 0) {
      int e0 = 0; float v0 = acc[0];
      #pragma unroll
      for (int e8 = 1; e8 < 8; ++e8) if (acc[e8] > v0) { v0 = acc[e8]; e0 = e8; }
      int e1 = -1; float v1 = -3.4e38f;
      #pragma unroll
      for (int e8 = 0; e8 < 8; ++e8) if (e8 != e0 && acc[e8] > v1) { v1 = acc[e8]; e1 = e8; }
      float g0 = 1.0f / (1.0f + expf(v1 - v0));   // = p0/(p0+p1) via softmax monotonicity
      eTok[ti * 2] = e0; eTok[ti * 2 + 1] = e1;
      gsv[t * 2] = g0;  gsv[t * 2 + 1] = 1.0f - g0;
    }
  }
  __syncthreads();
  if (wid == 0) {
    int cnts[8] = {0,0,0,0,0,0,0,0};
    int el[2];
    #pragma unroll
    for (int p = 0; p < 2; ++p) {
      el[p] = eTok[p * 64 + lane];
      #pragma unroll
      for (int e = 0; e < 8; ++e)
        cnts[e] += __popcll(__ballot(el[p] == e));
    }
    if (lane < 8) lbase[lane] = atomicAdd(&cnt[lane], cnts[lane]);
    int run[8];
    #pragma unroll
    for (int e = 0; e < 8; ++e) run[e] = lbase[e];   // LDS RAW within wave: HW-ordered
    #pragma unroll
    for (int p = 0; p < 2; ++p) {
      const int ent = p * 64 + lane;
      const int val = (tblk + (ent >> 1)) * 2 + (ent & 1);
      #pragma unroll
      for (int e = 0; e < 8; ++e) {
        unsigned long long m = __ballot(el[p] == e);
        if (el[p] == e)
          slots[e * MAXSLOT + run[e] + __popcll(m & ((1ull << lane) - 1ull))] = val;
        run[e] += __popcll(m);
      }
    }
  }
}

// 64x128 transpose tile: in [R][C] fp32 -> out [C][R] bf16, 16B stores.
__device__ __forceinline__ void t64x128(const float* __restrict__ in,
                                        ushort_t* __restrict__ out,
                                        int R, int C, int by, int bx,
                                        float* __restrict__ lds) {
  const int t = threadIdx.x;
  const int c4 = t & 31;
  const int r0 = t >> 5;
  const float* src = in + (size_t)(by * 64) * C + bx * 128;
  #pragma unroll
  for (int p = 0; p < 8; ++p) {
    const int r = r0 + p * 8;
    const float4 vv = *(const float4*)(src + (size_t)r * C + c4 * 4);
    *(float4*)(lds + r * 129 + c4 * 4) = vv;
  }
  __syncthreads();
  ushort_t* dst = out + (size_t)(bx * 128) * R + by * 64;
  const int rr0 = (t & 7) * 8;
  #pragma unroll
  for (int p = 0; p < 4; ++p) {
    const int cc = (t >> 3) + p * 32;
    const float* col = lds + (size_t)rr0 * 129 + cc;
    float f0 = col[0*129], f1 = col[1*129], f2 = col[2*129], f3 = col[3*129];
    float f4 = col[4*129], f5 = col[5*129], f6 = col[6*129], f7 = col[7*129];
    uint4 q;
    q.x = pk2bf(f0, f1); q.y = pk2bf(f2, f3);
    q.z = pk2bf(f4, f5); q.w = pk2bf(f6, f7);
    *(uint4*)(dst + (size_t)cc * R + rr0) = q;
  }
}

// ---------------- prep1: router FIRST, then cast, then W1t/We1t transposes ----------------
__global__ __launch_bounds__(256) void prep1_k(
    const float* __restrict__ x, ushort_t* __restrict__ xb,
    const float* __restrict__ Wg,
    int* __restrict__ cnt, int* __restrict__ slots, float* __restrict__ gsv,
    const float* __restrict__ W1, ushort_t* __restrict__ W1t,
    const float* __restrict__ We1, ushort_t* __restrict__ We1t)
{
  __shared__ char smemraw[64 * 129 * 4];
  const int wg = blockIdx.x;
  if (wg < 64) {
    router_dev(x, Wg, cnt, slots, gsv, wg,
               (int*)smemraw, (int*)(smemraw + 512));
  } else if (wg < 2112) {
    cast_dev(x, xb, wg - 64);
  } else if (wg < 2624) {               // W1: R=1024 C=4096, 16x32 tiles
    const int i = wg - 2112;
    t64x128(W1, W1t, Dd, DFFd, i >> 5, i & 31, (float*)smemraw);
  } else {                              // We1: 8 x (16x8 tiles)
    const int i = wg - 2624, z = i >> 7, rem = i & 127;
    t64x128(We1 + (size_t)z * Dd * DFEd, We1t + (size_t)z * Dd * DFEd,
            Dd, DFEd, rem >> 3, rem & 7, (float*)smemraw);
  }
}

// ================= 128x128 BK=64 m97-structure tile =================
// 4 waves (2x2 of 64x64), single-buffer 32KB LDS, 8-way XOR swizzle
// (source col pre-permuted, read XOR'd back).
// MODE 0: FFN1 gelu->bf16 | 1: FFN2 direct fp32 store | 2: MoE1 gather gelu->bf16
// MODE 3: MoE2 gather, eo[sv] = gate*(acc+bias)  (plain keyed store, no atomics)
template<int MODE>
__device__ __forceinline__ void gemm_tile(
    int nt, int mt, int e,
    const ushort_t* __restrict__ A, const ushort_t* __restrict__ Bt,
    const float* __restrict__ biase, void* __restrict__ C,
    int M, int lda, int N, int ldc,
    const int* __restrict__ cnt, const int* __restrict__ slots,
    const float* __restrict__ gates,
    ushort_t* Al, ushort_t* Bl)
{
  int rows = M;
  const int* slist = nullptr;
  if (MODE >= 2) {
    rows = cnt[e];
    if (mt * 128 >= rows) return;
    slist = slots + e * MAXSLOT;
  }
  const ushort_t* Bte = (MODE >= 2) ? (Bt + (size_t)e * (size_t)lda * (size_t)N) : Bt;

  const int tid  = threadIdx.x;
  const int lane = tid & 63;
  const int wid  = tid >> 6;
  const int wr   = wid >> 1, wc = wid & 1;
  const int lr   = lane & 15;
  const int lg   = lane >> 4;
  const int swz7 = lane & 7;   // == row&7 on the read side (rows stride 16)

  // --- staging source pointers: 4 slots/thread per matrix, pre-swizzled col ---
  const ushort_t* gA[4];
  const ushort_t* gB[4];
  #pragma unroll
  for (int j = 0; j < 4; ++j) {
    int tt = j * 256 + tid;
    int rl = tt >> 3, slot = tt & 7;
    int col8 = slot ^ (rl & 7);
    int grow = mt * 128 + rl;
    size_t rowoff;
    if (MODE < 2) {
      rowoff = (size_t)grow;
    } else {
      int idx = grow > rows - 1 ? rows - 1 : grow;
      int sv = slist[idx];
      if (MODE == 2) { int t = sv >> 1; rowoff = (size_t)((t >> 10) * Sseq + IDCUT + (t & 1023)); }
      else           { rowoff = (size_t)sv; }
    }
    gA[j] = A + rowoff * (size_t)lda + col8 * 8;
    gB[j] = Bte + (size_t)(nt * 128 + rl) * (size_t)lda + col8 * 8;
  }

  f32x4 acc[4][4];
  const f32x4 vzero = {0.f, 0.f, 0.f, 0.f};
  #pragma unroll
  for (int m = 0; m < 4; ++m)
    #pragma unroll
    for (int n = 0; n < 4; ++n) acc[m][n] = vzero;

  const unsigned aRow = (unsigned)((wr * 64 + lr) * 128);
  const unsigned bRow = (unsigned)((wc * 64 + lr) * 128);
  const unsigned s0 = (unsigned)((lg ^ swz7) << 4);        // ks=0 slot
  const unsigned s1 = (unsigned)(((4 + lg) ^ swz7) << 4);  // ks=1 slot

  for (int k0 = 0; k0 < lda; k0 += 64) {
    __syncthreads();
    #pragma unroll
    for (int j = 0; j < 4; ++j)
      gload_lds16(gA[j] + k0, (void*)((char*)Al + (j * 256 + wid * 64) * 16));
    #pragma unroll
    for (int j = 0; j < 4; ++j)
      gload_lds16(gB[j] + k0, (void*)((char*)Bl + (j * 256 + wid * 64) * 16));
    __syncthreads();   // compiler inserts vmcnt(0)+lgkmcnt(0) drain (m97 pattern)

    {  // ks = 0
      bf16x8v af[4], bfr[4];
      #pragma unroll
      for (int mi = 0; mi < 4; ++mi)
        af[mi] = *(const bf16x8v*)((const char*)Al + aRow + mi * 2048 + s0);
      #pragma unroll
      for (int ni = 0; ni < 4; ++ni)
        bfr[ni] = *(const bf16x8v*)((const char*)Bl + bRow + ni * 2048 + s0);
      #pragma unroll
      for (int mi = 0; mi < 4; ++mi)
        #pragma unroll
        for (int ni = 0; ni < 4; ++ni)
          acc[mi][ni] = __builtin_amdgcn_mfma_f32_16x16x32_bf16(
              af[mi], bfr[ni], acc[mi][ni], 0, 0, 0);
    }
    {  // ks = 1
      bf16x8v af[4], bfr[4];
      #pragma unroll
      for (int mi = 0; mi < 4; ++mi)
        af[mi] = *(const bf16x8v*)((const char*)Al + aRow + mi * 2048 + s1);
      #pragma unroll
      for (int ni = 0; ni < 4; ++ni)
        bfr[ni] = *(const bf16x8v*)((const char*)Bl + bRow + ni * 2048 + s1);
      #pragma unroll
      for (int mi = 0; mi < 4; ++mi)
        #pragma unroll
        for (int ni = 0; ni < 4; ++ni)
          acc[mi][ni] = __builtin_amdgcn_mfma_f32_16x16x32_bf16(
              af[mi], bfr[ni], acc[mi][ni], 0, 0, 0);
    }
  }

  // --- epilogue: C/D layout col = lane&15, row = (lane>>4)*4 + jj ---
  #pragma unroll
  for (int mf = 0; mf < 4; ++mf) {
    #pragma unroll
    for (int jj = 0; jj < 4; ++jj) {
      const int lrow = wr * 64 + mf * 16 + lg * 4 + jj;
      const int grow = mt * 128 + lrow;
      size_t crow; float gt = 0.f;
      if (MODE >= 2) {
        if (grow >= rows) continue;
        int sv = slist[grow];
        crow = (size_t)sv;
        if (MODE == 3) gt = gates[sv];
      } else {
        crow = (size_t)grow;
      }
      #pragma unroll
      for (int nf = 0; nf < 4; ++nf) {
        const int gcol = nt * 128 + wc * 64 + nf * 16 + lr;
        float v = acc[mf][nf][jj] + biase[gcol];
        if (MODE == 0 || MODE == 2) {
          ((ushort_t*)C)[crow * (size_t)ldc + gcol] = f2bf(gelu_f(v));
        } else if (MODE == 1) {
          ((float*)C)[crow * (size_t)ldc + gcol] = v;
        } else {
          ((float*)C)[crow * (size_t)ldc + gcol] = gt * v;   // eo, plain store
        }
      }
    }
  }
}

// FFN1 (2048) + MoE1 (2048) + W2t/We2t transpose backfill tail (1536).
// XCD-banded maps (XCD = blockIdx % 8):
//  FFN1: XCD owns mt-band; 8mt x 8nt co-resident squares (A+B ~ L2).
//  MoE1: expert e pinned to XCD e -> We1t[e] in one L2 only.
//  Tail transposes run in the drain tail; W2t/We2t consumed by NEXT launches.
__global__ __launch_bounds__(256, 3) void fused1_k(
    const ushort_t* __restrict__ xb,
    const ushort_t* __restrict__ W1t, const float* __restrict__ b1, ushort_t* __restrict__ h1,
    const ushort_t* __restrict__ We1t, const float* __restrict__ be1, ushort_t* __restrict__ hs,
    const int* __restrict__ cnt, const int* __restrict__ slots,
    const float* __restrict__ W2, ushort_t* __restrict__ W2t,
    const float* __restrict__ We2, ushort_t* __restrict__ We2t)
{
  __shared__ char smemraw[64 * 129 * 4];   // 33024B: max(GEMM 32KB, transpose 33KB)
  ushort_t* Al = (ushort_t*)smemraw;
  ushort_t* Bl = (ushort_t*)(smemraw + 16384);
  int wg = blockIdx.x;
  if (wg < 2048) {
    int xcd = wg & 7, idx = wg >> 3;            // idx in [0,256)
    int ntB = idx >> 6, mtL = (idx >> 3) & 7, ntS = idx & 7;
    int mt = xcd * 8 + mtL, nt = ntB * 8 + ntS;
    gemm_tile<0>(nt, mt, 0, xb, W1t, b1, (void*)h1, NTOK, Dd, DFFd, DFFd,
                 nullptr, nullptr, nullptr, Al, Bl);
  } else if (wg < 4096) {
    int i = wg - 2048;                          // i mod 8 == wg mod 8
    int e = i & 7, j = i >> 3;                  // j in [0,256)
    int mt = j >> 3, nt = j & 7;
    gemm_tile<2>(nt, mt, e, xb, We1t, be1 + e * DFEd, (void*)hs, 0, Dd, DFEd, DFEd,
                 cnt, slots, nullptr, Al, Bl);
  } else if (wg < 4608) {                       // W2: R=4096 C=1024, 64x8 tiles
    const int i = wg - 4096;
    t64x128(W2, W2t, DFFd, Dd, i >> 3, i & 7, (float*)smemraw);
  } else {                                      // We2: 8 x (16x8 tiles)
    const int i = wg - 4608, z = i >> 7, rem = i & 127;
    t64x128(We2 + (size_t)z * DFEd * Dd, We2t + (size_t)z * DFEd * Dd,
            DFEd, Dd, rem >> 3, rem & 7, (float*)smemraw);
  }
}

// FFN2 (512 long blocks, dispatched FIRST) + MoE2 (2048 short blocks backfill).
// Disjoint outputs (out vs eo) -> safe in one launch. (256,3): round-16's
// (256,4) capped regs at 128 -> acc spilled to scratch (VGPR 64, VALUBusy 9.5%,
// 160us). 3 blocks/CU is the sweet spot for this 136-reg kernel.
__global__ __launch_bounds__(256, 3) void fused2_k(
    const ushort_t* __restrict__ h1,
    const ushort_t* __restrict__ W2t, const float* __restrict__ b2,
    float* __restrict__ out,
    const ushort_t* __restrict__ hs,
    const ushort_t* __restrict__ We2t, const float* __restrict__ be2,
    float* __restrict__ eo,
    const int* __restrict__ cnt, const int* __restrict__ slots,
    const float* __restrict__ gsv)
{
  __shared__ ushort_t Al[128 * 64];
  __shared__ ushort_t Bl[128 * 64];
  int wg = blockIdx.x;
  if (wg < 512) {
    // FFN2: XCD owns mt-band [xcd*8, xcd*8+8) x all 8 nt (co-resident)
    int xcd = wg & 7, idx = wg >> 3;            // idx in [0,64)
    int nt = idx >> 3, mtL = idx & 7;
    int mt = xcd * 8 + mtL;
    gemm_tile<1>(nt, mt, 0, h1, W2t, b2, (void*)out, NTOK, DFFd, Dd, Dd,
                 nullptr, nullptr, nullptr, Al, Bl);
  } else {
    // MoE2: expert e pinned to XCD e; eo[sv] = gate*(acc+be2)
    int i = wg - 512;                           // i mod 8 == wg mod 8
    int e = i & 7, j = i >> 3;                  // j in [0,256)
    int mt = j >> 3, nt = j & 7;
    gemm_tile<3>(nt, mt, e, hs, We2t, be2 + e * Dd, (void*)eo, 0, DFEd, Dd, Dd,
                 cnt, slots, gsv, Al, Bl);
  }
}

// combine: out[moe rows] += LAM*(eo[2t] + eo[2t+1]); 4 float4/thread for ILP
__global__ __launch_bounds__(256) void combine_k(
    float* __restrict__ out, const float* __restrict__ eo)
{
  const int base = blockIdx.x * 256 + threadIdx.x;   // 1024 blocks
  #pragma unroll
  for (int p = 0; p < 4; ++p) {
    const int i = p * (1024 * 256) + base;           // stride passes: coalesced
    const int t = i >> 8;                            // 256 float4 per row
    const int c4 = i & 255;
    const size_t r = (size_t)((t >> 10) * Sseq + IDCUT + (t & 1023));
    const float4 a = ((const float4*)(eo + (size_t)(2 * t) * Dd))[c4];
    const float4 b = ((const float4*)(eo + (size_t)(2 * t + 1) * Dd))[c4];
    float4* op = (float4*)(out + r * Dd);
    float4 o = op[c4];
    o.x += 0.5f * (a.x + b.x);
    o.y += 0.5f * (a.y + b.y);
    o.z += 0.5f * (a.z + b.z);
    o.w += 0.5f * (a.w + b.w);
    op[c4] = o;
  }
}

// ---------------- workspace layout (bytes) ----------------
#define WS_XB    ((size_t)0)           // 16777216   xb bf16 [8192][1024]
#define WS_W1T   ((size_t)16777216)    //  8388608   W1^T bf16 [4096][1024]
#define WS_W2T   ((size_t)25165824)    //  8388608   W2^T bf16 [1024][4096]
#define WS_WE1T  ((size_t)33554432)    // 16777216   We1^T bf16 [8][1024][1024]
#define WS_WE2T  ((size_t)50331648)    // 16777216   We2^T bf16 [8][1024][1024]
#define WS_H1    ((size_t)67108864)    // 67108864   h1 bf16 [8192][4096]
#define WS_HS    ((size_t)134217728)   // 16777216   h_slot bf16 [8192][1024]
#define WS_EO    ((size_t)150994944)   // 33554432   eo fp32 [8192][1024]
#define WS_CNT   ((size_t)184549376)   // 256        cnt int[8]
#define WS_SLOT  ((size_t)184549632)   // 131072     slots int[8][4096]
#define WS_GSV   ((size_t)184680704)   // 32768      gate per slot fp32[8192]

extern "C" void kernel_launch(void* const* d_in, const int* in_sizes, int n_in,
                              void* d_out, int out_size, void* d_ws, size_t ws_size,
                              hipStream_t stream) {
  const float* x   = (const float*)d_in[0];
  const float* W1  = (const float*)d_in[1];
  const float* b1  = (const float*)d_in[2];
  const float* W2  = (const float*)d_in[3];
  const float* b2  = (const float*)d_in[4];
  const float* Wg  = (const float*)d_in[5];
  const float* We1 = (const float*)d_in[6];
  const float* be1 = (const float*)d_in[7];
  const float* We2 = (const float*)d_in[8];
  const float* be2 = (const float*)d_in[9];
  float* out = (float*)d_out;

  char* ws = (char*)d_ws;
  ushort_t* xb   = (ushort_t*)(ws + WS_XB);
  ushort_t* W1t  = (ushort_t*)(ws + WS_W1T);
  ushort_t* W2t  = (ushort_t*)(ws + WS_W2T);
  ushort_t* We1t = (ushort_t*)(ws + WS_WE1T);
  ushort_t* We2t = (ushort_t*)(ws + WS_WE2T);
  ushort_t* h1   = (ushort_t*)(ws + WS_H1);
  ushort_t* hs   = (ushort_t*)(ws + WS_HS);
  float*    eo   = (float*)(ws + WS_EO);
  int*      cnt  = (int*)(ws + WS_CNT);
  int*      slots= (int*)(ws + WS_SLOT);
  float*    gsv  = (float*)(ws + WS_GSV);

  hipMemsetAsync(cnt, 0, 8 * sizeof(int), stream);

  // prep1: router (64, first) + cast (2048) + W1t/We1t transposes (1536)
  prep1_k<<<dim3(3648), 256, 0, stream>>>(x, xb, Wg, cnt, slots, gsv,
                                          W1, W1t, We1, We1t);
  // FFN1 + MoE1 + W2t/We2t transpose backfill tail
  fused1_k<<<dim3(5632), 256, 0, stream>>>(xb, W1t, b1, h1, We1t, be1, hs,
                                           cnt, slots, W2, W2t, We2, We2t);
  // FFN2 (512, first) + MoE2 (2048, backfill) — disjoint outputs out / eo
  fused2_k<<<dim3(2560), 256, 0, stream>>>(h1, W2t, b2, out,
                                           hs, We2t, be2, eo, cnt, slots, gsv);
  // combine: out[moe rows] += LAM*(eo[2t]+eo[2t+1])
  combine_k<<<dim3(1024), 256, 0, stream>>>(out, eo);
}